// Round 2
// baseline (184.179 us; speedup 1.0000x reference)
//
#include <hip/hip_runtime.h>
#include <hip/hip_bf16.h>

typedef __attribute__((ext_vector_type(8))) short short8;   // 8 bf16 = MFMA A/B frag
typedef __attribute__((ext_vector_type(4))) short short4v;  // 4 bf16
typedef __attribute__((ext_vector_type(4))) float f32x4;    // MFMA C/D

#define MFMA16(A,B,C) __builtin_amdgcn_mfma_f32_16x16x32_bf16((A),(B),(C),0,0,0)

static __device__ __forceinline__ unsigned short f2bf(float f) {
  unsigned int u = __float_as_uint(f);
  unsigned int rnd = 0x7fffu + ((u >> 16) & 1u);   // round-to-nearest-even
  return (unsigned short)((u + rnd) >> 16);
}

// ---------------- prep: bf16 weights, pre-scaled/padded q, padded bias ----------------
__global__ void prep_kernel(const float* __restrict__ qg,
                            const float* __restrict__ wqkv,
                            const float* __restrict__ wproj,
                            const float* __restrict__ btab,
                            unsigned short* __restrict__ wq_bf,   // [384][192]
                            unsigned short* __restrict__ wp_bf,   // [192][192]
                            unsigned short* __restrict__ q_bf,    // [32][6][64][32]
                            float* __restrict__ bias_t)           // [6][64][64]
{
  const int t = blockIdx.x * 256 + threadIdx.x;
  if (t < 32*6*64*32) {
    const int d = t & 31, n = (t >> 5) & 63;
    const int bh = t >> 11;            // b*6 + h
    const int h = bh % 6, b = bh / 6;
    float v = 0.f;
    if (n < 49) v = qg[((b * 6 + h) * 49 + n) * 32 + d] * 0.17677669529663687f; // *D^-0.5
    q_bf[t] = f2bf(v);
  }
  if (t < 384*192) wq_bf[t] = f2bf(wqkv[t]);
  if (t < 192*192) wp_bf[t] = f2bf(wproj[t]);
  if (t < 6*64*64) {
    const int m = t & 63, n = (t >> 6) & 63, h = t >> 12;
    float v;
    if (m >= 49) v = -1e30f;           // mask padded keys
    else if (n >= 49) v = 0.f;         // padded query rows: anything finite
    else {
      const int ci = n / 7, cj = n % 7, mi = m / 7, mj = m % 7;
      const int idx = (ci - mi + 6) * 13 + (cj - mj + 6);
      v = btab[idx * 6 + h];
    }
    bias_t[t] = v;
  }
}

// ---------------- fused window attention ----------------
// LDS map (unsigned short elems):
//   x_lds  [64][200]           off 0      (25600 B)  -- aliased by p_lds in stage 3
//   k_lds  [6][64][36]         off 12800  (27648 B)
//   vT_lds [6][32][68]         off 26624  (26112 B)
//   o_lds  [64][200]           off 39680  (25600 B)
// total 52480 elems = 104960 B
__global__ __launch_bounds__(512, 2)
void fused_win_attn(const float* __restrict__ x,
                    const float* __restrict__ b_qkv,
                    const float* __restrict__ b_proj,
                    const unsigned short* __restrict__ wq_bf,
                    const unsigned short* __restrict__ wp_bf,
                    const unsigned short* __restrict__ q_bf,
                    const float* __restrict__ bias_t,
                    float* __restrict__ out)
{
  extern __shared__ unsigned short lds[];
  unsigned short* x_lds  = lds;
  unsigned short* k_lds  = lds + 12800;
  unsigned short* vT_lds = lds + 26624;
  unsigned short* o_lds  = lds + 39680;

  const f32x4 ZERO4 = {0.f, 0.f, 0.f, 0.f};

  const int tid = threadIdx.x;
  const int wv = tid >> 6;
  const int l  = tid & 63;
  const int lr = l & 15;
  const int lq = l >> 4;
  const int w  = blockIdx.x;

  // ---- stage 1: x -> LDS bf16, zero-pad rows 49..63
  {
    const float* xw = x + (size_t)w * (49 * 192);
    for (int i = tid; i < 2352; i += 512) {
      const float4 v = *reinterpret_cast<const float4*>(xw + i * 4);
      const int e = i * 4;
      const int row = e / 192, col = e % 192;
      short4v pk;
      pk[0] = (short)f2bf(v.x); pk[1] = (short)f2bf(v.y);
      pk[2] = (short)f2bf(v.z); pk[3] = (short)f2bf(v.w);
      *reinterpret_cast<short4v*>(&x_lds[row * 200 + col]) = pk;
    }
    for (int i = tid; i < 720; i += 512) {
      const int e = i * 4;
      const int row = 49 + e / 192, col = e % 192;
      short4v z = {0, 0, 0, 0};
      *reinterpret_cast<short4v*>(&x_lds[row * 200 + col]) = z;
    }
  }
  __syncthreads();

  // ---- stage 2: kv = x @ w_qkv^T + b_qkv  -> k_lds bf16, vT_lds bf16
  {
    short8 afr[4][6];
#pragma unroll
    for (int mt = 0; mt < 4; ++mt)
#pragma unroll
      for (int kb = 0; kb < 6; ++kb)
        afr[mt][kb] = *reinterpret_cast<const short8*>(
            &x_lds[(mt * 16 + lr) * 200 + kb * 32 + lq * 8]);

    for (int ct = 0; ct < 3; ++ct) {
      const int j = wv * 48 + ct * 16 + lr;   // 0..383
      short8 bfr[6];
#pragma unroll
      for (int kb = 0; kb < 6; ++kb)
        bfr[kb] = *reinterpret_cast<const short8*>(&wq_bf[j * 192 + kb * 32 + lq * 8]);
      const float bq = b_qkv[j];
      f32x4 acc[4];
#pragma unroll
      for (int mt = 0; mt < 4; ++mt) acc[mt] = ZERO4;
#pragma unroll
      for (int kb = 0; kb < 6; ++kb)
#pragma unroll
        for (int mt = 0; mt < 4; ++mt)
          acc[mt] = MFMA16(afr[mt][kb], bfr[kb], acc[mt]);

      if (j < 192) {                  // K path: k_lds[h][n][d]
        const int h = j >> 5, d = j & 31;
#pragma unroll
        for (int mt = 0; mt < 4; ++mt) {
          const int n0 = mt * 16 + lq * 4;
#pragma unroll
          for (int r = 0; r < 4; ++r)
            k_lds[h * 2304 + (n0 + r) * 36 + d] = f2bf(acc[mt][r] + bq);
        }
      } else {                        // V path: vT_lds[h][d][n], packed 4-row writes
        const int jj = j - 192, h = jj >> 5, d = jj & 31;
#pragma unroll
        for (int mt = 0; mt < 4; ++mt) {
          const int n0 = mt * 16 + lq * 4;
          short4v pk;
#pragma unroll
          for (int r = 0; r < 4; ++r) pk[r] = (short)f2bf(acc[mt][r] + bq);
          *reinterpret_cast<short4v*>(&vT_lds[h * 2176 + d * 68 + n0]) = pk;
        }
      }
    }
  }
  __syncthreads();

  // ---- stage 3: attention; wave owns row-tile nt = wv&3, heads {wv>>2 + 2*rd}
  unsigned short* p_lds = x_lds + wv * (16 * 72);   // per-wave [16][72] scratch (x is dead)
  const int nt = wv & 3;
  const int img = w >> 6;                            // rep = 64 windows per image
  for (int rd = 0; rd < 3; ++rd) {
    const int h = (wv >> 2) + 2 * rd;
    // QK^T: one MFMA per 16x16 tile (K = D = 32)
    const short8 aq = *reinterpret_cast<const short8*>(
        &q_bf[((img * 6 + h) * 64 + nt * 16 + lr) * 32 + lq * 8]);
    f32x4 s[4];
#pragma unroll
    for (int mt = 0; mt < 4; ++mt) {
      const unsigned short* kp = &k_lds[h * 2304 + (mt * 16 + lr) * 36 + lq * 8];
      const short4v k0 = *reinterpret_cast<const short4v*>(kp);
      const short4v k1 = *reinterpret_cast<const short4v*>(kp + 4);
      short8 bk;
      bk[0]=k0[0]; bk[1]=k0[1]; bk[2]=k0[2]; bk[3]=k0[3];
      bk[4]=k1[0]; bk[5]=k1[1]; bk[6]=k1[2]; bk[7]=k1[3];
      s[mt] = MFMA16(aq, bk, ZERO4);
    }
    // bias + row softmax (rows n = nt*16+lq*4+r live on 16 lanes sharing lq)
    const float* bp = bias_t + h * 4096 + (nt * 16 + lq * 4) * 64 + lr;
    float p[4][4];
    float rinv[4];
#pragma unroll
    for (int r = 0; r < 4; ++r) {
      float lg[4];
#pragma unroll
      for (int mt = 0; mt < 4; ++mt) lg[mt] = s[mt][r] + bp[r * 64 + mt * 16];
      float mx = fmaxf(fmaxf(lg[0], lg[1]), fmaxf(lg[2], lg[3]));
#pragma unroll
      for (int msk = 1; msk < 16; msk <<= 1) mx = fmaxf(mx, __shfl_xor(mx, msk, 64));
      float sum = 0.f;
#pragma unroll
      for (int mt = 0; mt < 4; ++mt) { p[r][mt] = __expf(lg[mt] - mx); sum += p[r][mt]; }
#pragma unroll
      for (int msk = 1; msk < 16; msk <<= 1) sum += __shfl_xor(sum, msk, 64);
      rinv[r] = 1.0f / sum;
    }
    // P (unnormalized) -> per-wave LDS [16][72]
#pragma unroll
    for (int r = 0; r < 4; ++r)
#pragma unroll
      for (int mt = 0; mt < 4; ++mt)
        p_lds[(lq * 4 + r) * 72 + mt * 16 + lr] = f2bf(p[r][mt]);
    // PV: O[16 x 32] = P[16 x 64] * V[64 x 32]
    f32x4 o0 = ZERO4, o1 = ZERO4;
#pragma unroll
    for (int kb = 0; kb < 2; ++kb) {
      const short8 pa = *reinterpret_cast<const short8*>(&p_lds[lr * 72 + kb * 32 + lq * 8]);
      const unsigned short* vp0 = &vT_lds[h * 2176 + lr * 68 + kb * 32 + lq * 8];
      const unsigned short* vp1 = &vT_lds[h * 2176 + (16 + lr) * 68 + kb * 32 + lq * 8];
      const short4v a0 = *reinterpret_cast<const short4v*>(vp0);
      const short4v a1 = *reinterpret_cast<const short4v*>(vp0 + 4);
      short8 bv0; bv0[0]=a0[0];bv0[1]=a0[1];bv0[2]=a0[2];bv0[3]=a0[3];
                  bv0[4]=a1[0];bv0[5]=a1[1];bv0[6]=a1[2];bv0[7]=a1[3];
      o0 = MFMA16(pa, bv0, o0);
      const short4v c0 = *reinterpret_cast<const short4v*>(vp1);
      const short4v c1 = *reinterpret_cast<const short4v*>(vp1 + 4);
      short8 bv1; bv1[0]=c0[0];bv1[1]=c0[1];bv1[2]=c0[2];bv1[3]=c0[3];
                  bv1[4]=c1[0];bv1[5]=c1[1];bv1[6]=c1[2];bv1[7]=c1[3];
      o1 = MFMA16(pa, bv1, o1);
    }
    // O -> o_lds (normalized), col = h*32 + d
#pragma unroll
    for (int r = 0; r < 4; ++r) {
      const int n = nt * 16 + lq * 4 + r;
      o_lds[n * 200 + h * 32 + lr]      = f2bf(o0[r] * rinv[r]);
      o_lds[n * 200 + h * 32 + 16 + lr] = f2bf(o1[r] * rinv[r]);
    }
  }
  __syncthreads();

  // ---- stage 4: out = o @ w_proj^T + b_proj
  {
    const int mt = wv & 3;
    const int ch = wv >> 2;
    short8 af[6];
#pragma unroll
    for (int kb = 0; kb < 6; ++kb)
      af[kb] = *reinterpret_cast<const short8*>(&o_lds[(mt * 16 + lr) * 200 + kb * 32 + lq * 8]);
    float* op = out + (size_t)w * 9408;
    for (int ct = 0; ct < 6; ++ct) {
      const int cp = ch * 96 + ct * 16 + lr;
      short8 bf[6];
#pragma unroll
      for (int kb = 0; kb < 6; ++kb)
        bf[kb] = *reinterpret_cast<const short8*>(&wp_bf[cp * 192 + kb * 32 + lq * 8]);
      f32x4 acc = ZERO4;
#pragma unroll
      for (int kb = 0; kb < 6; ++kb) acc = MFMA16(af[kb], bf[kb], acc);
      const float bb = b_proj[cp];
      const int n0 = mt * 16 + lq * 4;
#pragma unroll
      for (int r = 0; r < 4; ++r)
        if (n0 + r < 49) op[(n0 + r) * 192 + cp] = acc[r] + bb;
    }
  }
}

extern "C" void kernel_launch(void* const* d_in, const int* in_sizes, int n_in,
                              void* d_out, int out_size, void* d_ws, size_t ws_size,
                              hipStream_t stream) {
  const float* x     = (const float*)d_in[0];
  const float* qg    = (const float*)d_in[1];
  const float* wqkv  = (const float*)d_in[2];
  const float* bqkv  = (const float*)d_in[3];
  const float* btab  = (const float*)d_in[4];
  const float* wproj = (const float*)d_in[5];
  const float* bproj = (const float*)d_in[6];
  float* out = (float*)d_out;

  char* ws = (char*)d_ws;
  unsigned short* wq_bf = (unsigned short*)(ws);            // 147456 B
  unsigned short* wp_bf = (unsigned short*)(ws + 147456);   //  73728 B
  unsigned short* q_bf  = (unsigned short*)(ws + 221184);   // 786432 B
  float* bias_t         = (float*)(ws + 1007616);           //  98304 B (total 1105920 B)

  hipLaunchKernelGGL(prep_kernel, dim3(1536), dim3(256), 0, stream,
                     qg, wqkv, wproj, btab, wq_bf, wp_bf, q_bf, bias_t);
  hipLaunchKernelGGL(fused_win_attn, dim3(2048), dim3(512), 104960, stream,
                     x, bqkv, bproj, wq_bf, wp_bf, q_bf, bias_t, out);
}

// Round 3
// 144.456 us; speedup vs baseline: 1.2750x; 1.2750x over previous
//
#include <hip/hip_runtime.h>
#include <hip/hip_bf16.h>

typedef __attribute__((ext_vector_type(8))) short short8;   // 8 bf16 = MFMA A/B frag
typedef __attribute__((ext_vector_type(4))) short short4v;  // 4 bf16
typedef __attribute__((ext_vector_type(4))) float f32x4;    // MFMA C/D

#define MFMA16(A,B,C) __builtin_amdgcn_mfma_f32_16x16x32_bf16((A),(B),(C),0,0,0)

static __device__ __forceinline__ unsigned short f2bf(float f) {
  unsigned int u = __float_as_uint(f);
  unsigned int rnd = 0x7fffu + ((u >> 16) & 1u);   // round-to-nearest-even
  return (unsigned short)((u + rnd) >> 16);
}

// ---------------- prep: bf16 weights, pre-scaled/padded q, padded bias ----------------
__global__ void prep_kernel(const float* __restrict__ qg,
                            const float* __restrict__ wqkv,
                            const float* __restrict__ wproj,
                            const float* __restrict__ btab,
                            unsigned short* __restrict__ wq_bf,   // [384][192]
                            unsigned short* __restrict__ wp_bf,   // [192][192]
                            unsigned short* __restrict__ q_bf,    // [32][6][64][32]
                            float* __restrict__ bias_t)           // [6][64][64]
{
  const int t = blockIdx.x * 256 + threadIdx.x;
  if (t < 32*6*64*32) {
    const int d = t & 31, n = (t >> 5) & 63;
    const int bh = t >> 11;            // b*6 + h
    const int h = bh % 6, b = bh / 6;
    float v = 0.f;
    if (n < 49) v = qg[((b * 6 + h) * 49 + n) * 32 + d] * 0.17677669529663687f; // *D^-0.5
    q_bf[t] = f2bf(v);
  }
  if (t < 384*192) wq_bf[t] = f2bf(wqkv[t]);
  if (t < 192*192) wp_bf[t] = f2bf(wproj[t]);
  if (t < 6*64*64) {
    const int m = t & 63, n = (t >> 6) & 63, h = t >> 12;
    float v;
    if (m >= 49) v = -1e30f;           // mask padded keys
    else if (n >= 49) v = 0.f;         // padded query rows: anything finite
    else {
      const int ci = n / 7, cj = n % 7, mi = m / 7, mj = m % 7;
      const int idx = (ci - mi + 6) * 13 + (cj - mj + 6);
      v = btab[idx * 6 + h];
    }
    bias_t[t] = v;
  }
}

// ---------------- fused window attention ----------------
// LDS map (unsigned short elems):
//   x_lds  [64][200]           off 0      (25600 B)  -- aliased by p_lds in stage 3
//   k_lds  [6][64][36]         off 12800  (27648 B)  -- aliased by o_lds in stage 4
//   vT_lds [6][32][68]         off 26624  (26112 B)
//   o_lds  [64][200]           off 12800  (25600 B)  (aliases k_lds+vT_lds, after barrier)
// total 39680 elems = 79360 B -> 2 blocks/CU
__global__ __launch_bounds__(512, 4)
void fused_win_attn(const float* __restrict__ x,
                    const float* __restrict__ b_qkv,
                    const float* __restrict__ b_proj,
                    const unsigned short* __restrict__ wq_bf,
                    const unsigned short* __restrict__ wp_bf,
                    const unsigned short* __restrict__ q_bf,
                    const float* __restrict__ bias_t,
                    float* __restrict__ out)
{
  extern __shared__ unsigned short lds[];
  unsigned short* x_lds  = lds;
  unsigned short* k_lds  = lds + 12800;
  unsigned short* vT_lds = lds + 26624;
  unsigned short* o_lds  = lds + 12800;   // aliases k/vT after they are dead

  const f32x4 ZERO4 = {0.f, 0.f, 0.f, 0.f};

  const int tid = threadIdx.x;
  const int wv = tid >> 6;
  const int l  = tid & 63;
  const int lr = l & 15;
  const int lq = l >> 4;
  const int w  = blockIdx.x;

  // ---- stage 1: x -> LDS bf16, zero-pad rows 49..63
  {
    const float* xw = x + (size_t)w * (49 * 192);
    for (int i = tid; i < 2352; i += 512) {
      const float4 v = *reinterpret_cast<const float4*>(xw + i * 4);
      const int e = i * 4;
      const int row = e / 192, col = e % 192;
      short4v pk;
      pk[0] = (short)f2bf(v.x); pk[1] = (short)f2bf(v.y);
      pk[2] = (short)f2bf(v.z); pk[3] = (short)f2bf(v.w);
      *reinterpret_cast<short4v*>(&x_lds[row * 200 + col]) = pk;
    }
    for (int i = tid; i < 720; i += 512) {
      const int e = i * 4;
      const int row = 49 + e / 192, col = e % 192;
      short4v z = {0, 0, 0, 0};
      *reinterpret_cast<short4v*>(&x_lds[row * 200 + col]) = z;
    }
  }
  __syncthreads();

  // ---- stage 2: kv = x @ w_qkv^T + b_qkv  -> k_lds bf16, vT_lds bf16
  {
    short8 afr[4][6];
#pragma unroll
    for (int mt = 0; mt < 4; ++mt)
#pragma unroll
      for (int kb = 0; kb < 6; ++kb)
        afr[mt][kb] = *reinterpret_cast<const short8*>(
            &x_lds[(mt * 16 + lr) * 200 + kb * 32 + lq * 8]);

    for (int ct = 0; ct < 3; ++ct) {
      const int j = wv * 48 + ct * 16 + lr;   // 0..383
      short8 bfr[6];
#pragma unroll
      for (int kb = 0; kb < 6; ++kb)
        bfr[kb] = *reinterpret_cast<const short8*>(&wq_bf[j * 192 + kb * 32 + lq * 8]);
      const float bq = b_qkv[j];
      f32x4 acc[4];
#pragma unroll
      for (int mt = 0; mt < 4; ++mt) acc[mt] = ZERO4;
#pragma unroll
      for (int kb = 0; kb < 6; ++kb)
#pragma unroll
        for (int mt = 0; mt < 4; ++mt)
          acc[mt] = MFMA16(afr[mt][kb], bfr[kb], acc[mt]);

      if (j < 192) {                  // K path: k_lds[h][n][d]
        const int h = j >> 5, d = j & 31;
#pragma unroll
        for (int mt = 0; mt < 4; ++mt) {
          const int n0 = mt * 16 + lq * 4;
#pragma unroll
          for (int r = 0; r < 4; ++r)
            k_lds[h * 2304 + (n0 + r) * 36 + d] = f2bf(acc[mt][r] + bq);
        }
      } else {                        // V path: vT_lds[h][d][n], packed 4-row writes
        const int jj = j - 192, h = jj >> 5, d = jj & 31;
#pragma unroll
        for (int mt = 0; mt < 4; ++mt) {
          const int n0 = mt * 16 + lq * 4;
          short4v pk;
#pragma unroll
          for (int r = 0; r < 4; ++r) pk[r] = (short)f2bf(acc[mt][r] + bq);
          *reinterpret_cast<short4v*>(&vT_lds[h * 2176 + d * 68 + n0]) = pk;
        }
      }
    }
  }
  __syncthreads();

  // ---- stage 3: attention; wave owns row-tile nt = wv&3, heads {wv>>2 + 2*rd}
  // O kept in registers (normalized) until k/vT are dead, then written to aliased LDS.
  unsigned short* p_lds = x_lds + wv * (16 * 72);   // per-wave [16][72] scratch (x is dead)
  const int nt = wv & 3;
  const int img = w >> 6;                            // rep = 64 windows per image
  f32x4 o_reg[3][2];
#pragma unroll
  for (int rd = 0; rd < 3; ++rd) {
    const int h = (wv >> 2) + 2 * rd;
    // QK^T: one MFMA per 16x16 tile (K = D = 32)
    const short8 aq = *reinterpret_cast<const short8*>(
        &q_bf[((img * 6 + h) * 64 + nt * 16 + lr) * 32 + lq * 8]);
    f32x4 s[4];
#pragma unroll
    for (int mt = 0; mt < 4; ++mt) {
      const unsigned short* kp = &k_lds[h * 2304 + (mt * 16 + lr) * 36 + lq * 8];
      const short4v k0 = *reinterpret_cast<const short4v*>(kp);
      const short4v k1 = *reinterpret_cast<const short4v*>(kp + 4);
      short8 bk;
      bk[0]=k0[0]; bk[1]=k0[1]; bk[2]=k0[2]; bk[3]=k0[3];
      bk[4]=k1[0]; bk[5]=k1[1]; bk[6]=k1[2]; bk[7]=k1[3];
      s[mt] = MFMA16(aq, bk, ZERO4);
    }
    // bias + row softmax (rows n = nt*16+lq*4+r live on 16 lanes sharing lq)
    const float* bp = bias_t + h * 4096 + (nt * 16 + lq * 4) * 64 + lr;
    float p[4][4];
    float rinv[4];
#pragma unroll
    for (int r = 0; r < 4; ++r) {
      float lg[4];
#pragma unroll
      for (int mt = 0; mt < 4; ++mt) lg[mt] = s[mt][r] + bp[r * 64 + mt * 16];
      float mx = fmaxf(fmaxf(lg[0], lg[1]), fmaxf(lg[2], lg[3]));
#pragma unroll
      for (int msk = 1; msk < 16; msk <<= 1) mx = fmaxf(mx, __shfl_xor(mx, msk, 64));
      float sum = 0.f;
#pragma unroll
      for (int mt = 0; mt < 4; ++mt) { p[r][mt] = __expf(lg[mt] - mx); sum += p[r][mt]; }
#pragma unroll
      for (int msk = 1; msk < 16; msk <<= 1) sum += __shfl_xor(sum, msk, 64);
      rinv[r] = 1.0f / sum;
    }
    // P (unnormalized) -> per-wave LDS [16][72]
#pragma unroll
    for (int r = 0; r < 4; ++r)
#pragma unroll
      for (int mt = 0; mt < 4; ++mt)
        p_lds[(lq * 4 + r) * 72 + mt * 16 + lr] = f2bf(p[r][mt]);
    // PV: O[16 x 32] = P[16 x 64] * V[64 x 32]
    f32x4 o0 = ZERO4, o1 = ZERO4;
#pragma unroll
    for (int kb = 0; kb < 2; ++kb) {
      const short8 pa = *reinterpret_cast<const short8*>(&p_lds[lr * 72 + kb * 32 + lq * 8]);
      const unsigned short* vp0 = &vT_lds[h * 2176 + lr * 68 + kb * 32 + lq * 8];
      const unsigned short* vp1 = &vT_lds[h * 2176 + (16 + lr) * 68 + kb * 32 + lq * 8];
      const short4v a0 = *reinterpret_cast<const short4v*>(vp0);
      const short4v a1 = *reinterpret_cast<const short4v*>(vp0 + 4);
      short8 bv0; bv0[0]=a0[0];bv0[1]=a0[1];bv0[2]=a0[2];bv0[3]=a0[3];
                  bv0[4]=a1[0];bv0[5]=a1[1];bv0[6]=a1[2];bv0[7]=a1[3];
      o0 = MFMA16(pa, bv0, o0);
      const short4v c0 = *reinterpret_cast<const short4v*>(vp1);
      const short4v c1 = *reinterpret_cast<const short4v*>(vp1 + 4);
      short8 bv1; bv1[0]=c0[0];bv1[1]=c0[1];bv1[2]=c0[2];bv1[3]=c0[3];
                  bv1[4]=c1[0];bv1[5]=c1[1];bv1[6]=c1[2];bv1[7]=c1[3];
      o1 = MFMA16(pa, bv1, o1);
    }
#pragma unroll
    for (int r = 0; r < 4; ++r) {
      o_reg[rd][0][r] = o0[r] * rinv[r];
      o_reg[rd][1][r] = o1[r] * rinv[r];
    }
  }
  __syncthreads();   // all reads of k_lds/vT_lds complete

  // ---- write O (registers) -> o_lds aliasing dead k/vT region
#pragma unroll
  for (int rd = 0; rd < 3; ++rd) {
    const int h = (wv >> 2) + 2 * rd;
#pragma unroll
    for (int r = 0; r < 4; ++r) {
      const int n = nt * 16 + lq * 4 + r;
      o_lds[n * 200 + h * 32 + lr]      = f2bf(o_reg[rd][0][r]);
      o_lds[n * 200 + h * 32 + 16 + lr] = f2bf(o_reg[rd][1][r]);
    }
  }
  __syncthreads();

  // ---- stage 4: out = o @ w_proj^T + b_proj
  {
    const int mt = wv & 3;
    const int ch = wv >> 2;
    short8 af[6];
#pragma unroll
    for (int kb = 0; kb < 6; ++kb)
      af[kb] = *reinterpret_cast<const short8*>(&o_lds[(mt * 16 + lr) * 200 + kb * 32 + lq * 8]);
    float* op = out + (size_t)w * 9408;
    for (int ct = 0; ct < 6; ++ct) {
      const int cp = ch * 96 + ct * 16 + lr;
      short8 bf[6];
#pragma unroll
      for (int kb = 0; kb < 6; ++kb)
        bf[kb] = *reinterpret_cast<const short8*>(&wp_bf[cp * 192 + kb * 32 + lq * 8]);
      f32x4 acc = ZERO4;
#pragma unroll
      for (int kb = 0; kb < 6; ++kb) acc = MFMA16(af[kb], bf[kb], acc);
      const float bb = b_proj[cp];
      const int n0 = mt * 16 + lq * 4;
#pragma unroll
      for (int r = 0; r < 4; ++r)
        if (n0 + r < 49) op[(n0 + r) * 192 + cp] = acc[r] + bb;
    }
  }
}

extern "C" void kernel_launch(void* const* d_in, const int* in_sizes, int n_in,
                              void* d_out, int out_size, void* d_ws, size_t ws_size,
                              hipStream_t stream) {
  const float* x     = (const float*)d_in[0];
  const float* qg    = (const float*)d_in[1];
  const float* wqkv  = (const float*)d_in[2];
  const float* bqkv  = (const float*)d_in[3];
  const float* btab  = (const float*)d_in[4];
  const float* wproj = (const float*)d_in[5];
  const float* bproj = (const float*)d_in[6];
  float* out = (float*)d_out;

  char* ws = (char*)d_ws;
  unsigned short* wq_bf = (unsigned short*)(ws);            // 147456 B
  unsigned short* wp_bf = (unsigned short*)(ws + 147456);   //  73728 B
  unsigned short* q_bf  = (unsigned short*)(ws + 221184);   // 786432 B
  float* bias_t         = (float*)(ws + 1007616);           //  98304 B (total 1105920 B)

  hipLaunchKernelGGL(prep_kernel, dim3(1536), dim3(256), 0, stream,
                     qg, wqkv, wproj, btab, wq_bf, wp_bf, q_bf, bias_t);
  hipLaunchKernelGGL(fused_win_attn, dim3(2048), dim3(512), 79360, stream,
                     x, bqkv, bproj, wq_bf, wp_bf, q_bf, bias_t, out);
}